// Round 2
// baseline (493.089 us; speedup 1.0000x reference)
//
#include <hip/hip_runtime.h>
#include <cstdint>

#define L_NUM 12
#define B_NUM 1024
#define P_NUM 100
#define LP_NUM 8
#define D_NUM 768
#define TILE_E (LP_NUM * D_NUM)   // 6144 floats per (l,b) output tile
#define TOPK 5
#define GQ 8                      // queries per score-block
#define EPSF 1e-12f

// monotonic key: larger score -> larger key; ties -> lower index wins
__device__ __forceinline__ unsigned long long makeKey(float f, int p) {
    union { float f; uint32_t u; } v; v.f = f;
    uint32_t u = v.u;
    u = (u & 0x80000000u) ? ~u : (u | 0x80000000u);
    return ((unsigned long long)u << 32) | (unsigned)(127 - p);
}

// ---- Kernel 1: per-(l,p) stats: invK = 1/max(||K||,eps), s = <Kn, An> ----
__global__ __launch_bounds__(64) void proto_stats_kernel(
    const float* __restrict__ K, const float* __restrict__ A,
    float* __restrict__ invK, float* __restrict__ sArr)
{
    const int lp = blockIdx.x;          // l*P_NUM + p
    const int lane = threadIdx.x;
    const float4* Kp = (const float4*)(K + (size_t)lp * D_NUM);
    const float4* Ap = (const float4*)(A + (size_t)lp * D_NUM);
    float kk = 0.f, aa = 0.f, ka = 0.f;
#pragma unroll
    for (int c = 0; c < 3; c++) {
        float4 k4 = Kp[c * 64 + lane];
        float4 a4 = Ap[c * 64 + lane];
        kk += k4.x * k4.x + k4.y * k4.y + k4.z * k4.z + k4.w * k4.w;
        aa += a4.x * a4.x + a4.y * a4.y + a4.z * a4.z + a4.w * a4.w;
        ka += k4.x * a4.x + k4.y * a4.y + k4.z * a4.z + k4.w * a4.w;
    }
#pragma unroll
    for (int off = 32; off; off >>= 1) {
        kk += __shfl_xor(kk, off);
        aa += __shfl_xor(aa, off);
        ka += __shfl_xor(ka, off);
    }
    if (lane == 0) {
        float nk = fmaxf(sqrtf(kk), EPSF);
        float na = fmaxf(sqrtf(aa), EPSF);
        invK[lp] = 1.0f / nk;
        sArr[lp] = ka / (nk * na);
    }
}

// ---- Kernel 2: scores (GQ queries per block) + top-5 -> ws ----
__global__ __launch_bounds__(256) void scores_top5_kernel(
    const float* __restrict__ X,     // [B, L, D]
    const float* __restrict__ K,     // [L, P, D]
    const float* __restrict__ invK,  // [L*P]
    const float* __restrict__ sArr,  // [L*P]
    int*   __restrict__ topIdx,      // [L*B, 5]
    float* __restrict__ topW)        // [L*B, 5]
{
    const int b0 = blockIdx.x * GQ;
    const int l  = blockIdx.y;
    const int tid = threadIdx.x;
    const int lane = tid & 63;
    const int w = tid >> 6;           // wave 0..3

    __shared__ float sc[GQ][P_NUM];

    // load GQ query rows into registers (chunked across lanes, float4)
    float4 q[GQ][3];
#pragma unroll
    for (int g = 0; g < GQ; g++) {
        const float4* Q = (const float4*)(X + ((size_t)(b0 + g) * L_NUM + l) * D_NUM);
#pragma unroll
        for (int c = 0; c < 3; c++) q[g][c] = Q[c * 64 + lane];
    }

    // each wave: 25 prototypes; dot against all GQ queries
    for (int i = 0; i < 25; i++) {
        const int p = w * 25 + i;
        const float4* Kp = (const float4*)(K + ((size_t)l * P_NUM + p) * D_NUM);
        float4 kv0 = Kp[0 * 64 + lane];
        float4 kv1 = Kp[1 * 64 + lane];
        float4 kv2 = Kp[2 * 64 + lane];
        float acc[GQ];
#pragma unroll
        for (int g = 0; g < GQ; g++) {
            acc[g] = q[g][0].x * kv0.x + q[g][0].y * kv0.y + q[g][0].z * kv0.z + q[g][0].w * kv0.w
                   + q[g][1].x * kv1.x + q[g][1].y * kv1.y + q[g][1].z * kv1.z + q[g][1].w * kv1.w
                   + q[g][2].x * kv2.x + q[g][2].y * kv2.y + q[g][2].z * kv2.z + q[g][2].w * kv2.w;
        }
#pragma unroll
        for (int off = 32; off; off >>= 1) {
#pragma unroll
            for (int g = 0; g < GQ; g++) acc[g] += __shfl_xor(acc[g], off);
        }
        if (lane == 0) {
            const float s = invK[l * P_NUM + p];
#pragma unroll
            for (int g = 0; g < GQ; g++) sc[g][p] = acc[g] * s;
        }
    }
    __syncthreads();

    // top-5 per query: wave w handles g = w and g = w+4
#pragma unroll
    for (int pass = 0; pass < 2; pass++) {
        const int g = w + pass * 4;
        float s0 = sc[g][lane];
        float s1 = (lane + 64 < P_NUM) ? sc[g][lane + 64] : -3.0e38f;
        unsigned long long k0 = makeKey(s0, lane);
        unsigned long long k1 = makeKey(s1, lane + 64);
        const size_t base = ((size_t)l * B_NUM + (b0 + g)) * TOPK;
        for (int j = 0; j < TOPK; j++) {
            unsigned long long m = k0 > k1 ? k0 : k1;
#pragma unroll
            for (int off = 32; off; off >>= 1) {
                unsigned long long o = __shfl_xor(m, off);
                if (o > m) m = o;
            }
            if (k0 == m) k0 = 0ull;
            if (k1 == m) k1 = 0ull;
            if (lane == 0) {
                int p = 127 - (int)(m & 127ull);
                topIdx[base + j] = p;
                topW[base + j]   = sArr[l * P_NUM + p];
            }
        }
    }
}

// ---- Kernel 3: weighted gather of P rows -> output tile ----
__global__ __launch_bounds__(256) void gather_out_kernel(
    const float* __restrict__ Pall,   // [L, P, Lp, D]
    const int*   __restrict__ topIdx, // [L*B, 5]
    const float* __restrict__ topW,   // [L*B, 5]
    float* __restrict__ out)          // [L, B, Lp, D]
{
    const int b = blockIdx.x;
    const int l = blockIdx.y;
    const int tid = threadIdx.x;
    const size_t lb = (size_t)l * B_NUM + b;

    int   pk[TOPK];
    float wk[TOPK];
#pragma unroll
    for (int j = 0; j < TOPK; j++) {
        pk[j] = topIdx[lb * TOPK + j];
        wk[j] = topW[lb * TOPK + j];
    }

    const float* Pl = Pall + (size_t)l * P_NUM * TILE_E;
    const float4* Pr[TOPK];
#pragma unroll
    for (int j = 0; j < TOPK; j++) Pr[j] = (const float4*)(Pl + (size_t)pk[j] * TILE_E);

    float4* outv = (float4*)(out + lb * TILE_E);

    // 6144 floats = 1536 float4; 256 threads x 6 iterations
#pragma unroll
    for (int it = 0; it < 6; it++) {
        const int e4 = it * 256 + tid;
        float4 r = make_float4(0.f, 0.f, 0.f, 0.f);
#pragma unroll
        for (int j = 0; j < TOPK; j++) {
            const float4 pu = Pr[j][e4];
            const float wj = wk[j];
            r.x += wj * pu.x; r.y += wj * pu.y; r.z += wj * pu.z; r.w += wj * pu.w;
        }
        outv[e4] = r;
    }
}

extern "C" void kernel_launch(void* const* d_in, const int* in_sizes, int n_in,
                              void* d_out, int out_size, void* d_ws, size_t ws_size,
                              hipStream_t stream) {
    const float* X  = (const float*)d_in[0];  // x_query [B,L,D]
    const float* K  = (const float*)d_in[1];  // K_all   [L,P,D]
    const float* A  = (const float*)d_in[2];  // A_all   [L,P,D]
    const float* Pp = (const float*)d_in[3];  // P_all   [L,P,Lp,D]

    float* invK  = (float*)d_ws;                       // 1200 floats
    float* sArr  = invK + L_NUM * P_NUM;               // 1200 floats
    int*   topIdx = (int*)(sArr + L_NUM * P_NUM);      // 12288*5 ints
    float* topW  = (float*)(topIdx + L_NUM * B_NUM * TOPK); // 12288*5 floats

    proto_stats_kernel<<<L_NUM * P_NUM, 64, 0, stream>>>(K, A, invK, sArr);
    scores_top5_kernel<<<dim3(B_NUM / GQ, L_NUM), 256, 0, stream>>>(
        X, K, invK, sArr, topIdx, topW);
    gather_out_kernel<<<dim3(B_NUM, L_NUM), 256, 0, stream>>>(
        Pp, topIdx, topW, (float*)d_out);
}

// Round 3
// 478.682 us; speedup vs baseline: 1.0301x; 1.0301x over previous
//
#include <hip/hip_runtime.h>
#include <cstdint>

#define L_NUM 12
#define B_NUM 1024
#define P_NUM 100
#define LP_NUM 8
#define D_NUM 768
#define TILE_E (LP_NUM * D_NUM)   // 6144 floats per (l,b) output tile
#define TOPK 5
#define GQ 8                      // queries per block
#define EPSF 1e-12f

// monotonic key: larger score -> larger key; ties -> lower index wins
__device__ __forceinline__ unsigned long long makeKey(float f, int p) {
    union { float f; uint32_t u; } v; v.f = f;
    uint32_t u = v.u;
    u = (u & 0x80000000u) ? ~u : (u | 0x80000000u);
    return ((unsigned long long)u << 32) | (unsigned)(127 - p);
}

// ---- Kernel 1: per-(l,p) stats: invK = 1/max(||K||,eps), s = <Kn, An> ----
__global__ __launch_bounds__(64) void proto_stats_kernel(
    const float* __restrict__ K, const float* __restrict__ A,
    float* __restrict__ invK, float* __restrict__ sArr)
{
    const int lp = blockIdx.x;          // l*P_NUM + p
    const int lane = threadIdx.x;
    const float4* Kp = (const float4*)(K + (size_t)lp * D_NUM);
    const float4* Ap = (const float4*)(A + (size_t)lp * D_NUM);
    float kk = 0.f, aa = 0.f, ka = 0.f;
#pragma unroll
    for (int c = 0; c < 3; c++) {
        float4 k4 = Kp[c * 64 + lane];
        float4 a4 = Ap[c * 64 + lane];
        kk += k4.x * k4.x + k4.y * k4.y + k4.z * k4.z + k4.w * k4.w;
        aa += a4.x * a4.x + a4.y * a4.y + a4.z * a4.z + a4.w * a4.w;
        ka += k4.x * a4.x + k4.y * a4.y + k4.z * a4.z + k4.w * a4.w;
    }
#pragma unroll
    for (int off = 32; off; off >>= 1) {
        kk += __shfl_xor(kk, off);
        aa += __shfl_xor(aa, off);
        ka += __shfl_xor(ka, off);
    }
    if (lane == 0) {
        float nk = fmaxf(sqrtf(kk), EPSF);
        float na = fmaxf(sqrtf(aa), EPSF);
        invK[lp] = 1.0f / nk;
        sArr[lp] = ka / (nk * na);
    }
}

// ---- Kernel 2: fused scores + top-5 + weighted gather-out ----
__global__ __launch_bounds__(256) void fused_main_kernel(
    const float* __restrict__ X,     // [B, L, D]
    const float* __restrict__ K,     // [L, P, D]
    const float* __restrict__ Pall,  // [L, P, Lp, D]
    const float* __restrict__ invK,  // [L*P]
    const float* __restrict__ sArr,  // [L*P]
    float* __restrict__ out)         // [L, B, Lp, D]
{
    const int b0 = blockIdx.x * GQ;
    const int l  = blockIdx.y;
    const int tid = threadIdx.x;
    const int lane = tid & 63;
    const int w = tid >> 6;           // wave 0..3

    __shared__ float sc[GQ][P_NUM];
    __shared__ int   idx_s[GQ][TOPK];
    __shared__ float wgt_s[GQ][TOPK];

    // ---- phase 1: scores. GQ query rows in registers (float4-chunked). ----
    float4 q[GQ][3];
#pragma unroll
    for (int g = 0; g < GQ; g++) {
        const float4* Q = (const float4*)(X + ((size_t)(b0 + g) * L_NUM + l) * D_NUM);
#pragma unroll
        for (int c = 0; c < 3; c++) q[g][c] = Q[c * 64 + lane];
    }

    // each wave: 25 prototypes; dot against all GQ queries
    for (int i = 0; i < 25; i++) {
        const int p = w * 25 + i;
        const float4* Kp = (const float4*)(K + ((size_t)l * P_NUM + p) * D_NUM);
        float4 kv0 = Kp[0 * 64 + lane];
        float4 kv1 = Kp[1 * 64 + lane];
        float4 kv2 = Kp[2 * 64 + lane];
        float acc[GQ];
#pragma unroll
        for (int g = 0; g < GQ; g++) {
            acc[g] = q[g][0].x * kv0.x + q[g][0].y * kv0.y + q[g][0].z * kv0.z + q[g][0].w * kv0.w
                   + q[g][1].x * kv1.x + q[g][1].y * kv1.y + q[g][1].z * kv1.z + q[g][1].w * kv1.w
                   + q[g][2].x * kv2.x + q[g][2].y * kv2.y + q[g][2].z * kv2.z + q[g][2].w * kv2.w;
        }
#pragma unroll
        for (int off = 32; off; off >>= 1) {
#pragma unroll
            for (int g = 0; g < GQ; g++) acc[g] += __shfl_xor(acc[g], off);
        }
        if (lane == 0) {
            const float s = invK[l * P_NUM + p];
#pragma unroll
            for (int g = 0; g < GQ; g++) sc[g][p] = acc[g] * s;
        }
    }
    __syncthreads();

    // ---- phase 2: top-5 per query (wave w handles g = w and g = w+4) ----
#pragma unroll
    for (int pass = 0; pass < 2; pass++) {
        const int g = w + pass * 4;
        float s0 = sc[g][lane];
        float s1 = (lane + 64 < P_NUM) ? sc[g][lane + 64] : -3.0e38f;
        unsigned long long k0 = makeKey(s0, lane);
        unsigned long long k1 = makeKey(s1, lane + 64);
        for (int j = 0; j < TOPK; j++) {
            unsigned long long m = k0 > k1 ? k0 : k1;
#pragma unroll
            for (int off = 32; off; off >>= 1) {
                unsigned long long o = __shfl_xor(m, off);
                if (o > m) m = o;
            }
            if (k0 == m) k0 = 0ull;
            if (k1 == m) k1 = 0ull;
            if (lane == 0) {
                int p = 127 - (int)(m & 127ull);
                idx_s[g][j] = p;
                wgt_s[g][j] = sArr[l * P_NUM + p];
            }
        }
    }
    __syncthreads();

    // ---- phase 3: weighted gather-out, all 256 threads per tile ----
    const float* Pl = Pall + (size_t)l * P_NUM * TILE_E;
#pragma unroll
    for (int g = 0; g < GQ; g++) {
        const float4* Pr[TOPK];
        float wk[TOPK];
#pragma unroll
        for (int j = 0; j < TOPK; j++) {
            Pr[j] = (const float4*)(Pl + (size_t)idx_s[g][j] * TILE_E);
            wk[j] = wgt_s[g][j];
        }
        float4* outv = (float4*)(out + ((size_t)l * B_NUM + (b0 + g)) * TILE_E);
        // 6144 floats = 1536 float4; 256 threads x 6 iterations
#pragma unroll
        for (int it = 0; it < 6; it++) {
            const int e4 = it * 256 + tid;
            float4 r = make_float4(0.f, 0.f, 0.f, 0.f);
#pragma unroll
            for (int j = 0; j < TOPK; j++) {
                const float4 pu = Pr[j][e4];
                const float wj = wk[j];
                r.x += wj * pu.x; r.y += wj * pu.y; r.z += wj * pu.z; r.w += wj * pu.w;
            }
            outv[e4] = r;
        }
    }
}

extern "C" void kernel_launch(void* const* d_in, const int* in_sizes, int n_in,
                              void* d_out, int out_size, void* d_ws, size_t ws_size,
                              hipStream_t stream) {
    const float* X  = (const float*)d_in[0];  // x_query [B,L,D]
    const float* K  = (const float*)d_in[1];  // K_all   [L,P,D]
    const float* A  = (const float*)d_in[2];  // A_all   [L,P,D]
    const float* Pp = (const float*)d_in[3];  // P_all   [L,P,Lp,D]

    float* invK = (float*)d_ws;               // 1200 floats
    float* sArr = invK + L_NUM * P_NUM;       // 1200 floats

    proto_stats_kernel<<<L_NUM * P_NUM, 64, 0, stream>>>(K, A, invK, sArr);
    fused_main_kernel<<<dim3(B_NUM / GQ, L_NUM), 256, 0, stream>>>(
        X, K, Pp, invK, sArr, (float*)d_out);
}